// Round 12
// baseline (15963.188 us; speedup 1.0000x reference)
//
#include <hip/hip_runtime.h>
#include <math.h>

#define NS 512
#define NE 2048
#define NB 64
#define NT 512

// out[c][r] = in[r][c]; rows, cols multiples of 32
__global__ __launch_bounds__(256) void transpose_k(const float* __restrict__ in,
                                                   float* __restrict__ out,
                                                   int rows, int cols) {
  __shared__ float tile[32][33];
  int c0 = blockIdx.x * 32;
  int r0 = blockIdx.y * 32;
  int tx = threadIdx.x;  // 0..31
  int ty = threadIdx.y;  // 0..7
#pragma unroll
  for (int k = 0; k < 32; k += 8) {
    tile[ty + k][tx] = in[(size_t)(r0 + ty + k) * cols + (c0 + tx)];
  }
  __syncthreads();
#pragma unroll
  for (int k = 0; k < 32; k += 8) {
    out[(size_t)(c0 + ty + k) * rows + (r0 + tx)] = tile[tx][ty + k];
  }
}

// Forward, LDS-resident T-slice. 32 groups x 8 members (bid = g + 32*m, all
// members of a group on one XCD). Member m owns columns [64m,64m+64) for
// batches bA=g, bB=g+32; its full T-slice (512 rows x 64 cols = 128 KB) is
// staged ONCE in LDS (guaranteed residency; VGPR residency refused by the
// compiler in R3/R4/R5/R6/R11).
// Thread (oct=tid>>6, jl=tid&63): column j=64m+jl, i-block ib=(m+oct)&7.
// KEY: wave r consumes exactly the v-slice it gathers -> gather needs no
// cross-wave barrier (same-wave ds_write/ds_read), and wave r polls only its
// source member's flag (7 parallel single-address polls).
// Per iteration (one timestep for BOTH batches):
//   A: [waves>0: poll flA[ib] >= t-1, acquire, gather 1 elem/lane, stage]
//      computeA from LDS (T-slice + own staging) -> pA ; barrier1
//   EA (wave0: reduce pA + eA, stage own, publish v[t][bA], release flA[m])
//      || [waves>0: poll/gather/stage B]  ; computeB -> pB ; barrier2
//   EB (wave0, same for B, release flB[m]) ; barrier3 (pA/pB reuse guard)
// Flags monotonic; exchange medium = time-indexed checkpoint v[t] (write-once).
__global__ __launch_bounds__(512) void viterbi_fwd(
    const int* __restrict__ obs,     // [NB][NT]
    const float* __restrict__ start, // [NS]
    const float* __restrict__ trans, // [NS][NS]
    const float* __restrict__ emT,   // [NE][NS]
    float* __restrict__ v,           // [NT][NB][NS] checkpoints + exchange
    int* __restrict__ flags)         // [32][16], zeroed before launch
{
  const int g = blockIdx.x & 31;
  const int m = blockIdx.x >> 5;       // member 0..7
  const int tid = threadIdx.x;
  const int jl = tid & 63;
  const int oct = tid >> 6;            // wave 0..7
  const int ib = (m + oct) & 7;        // i-block this thread covers (= source member)
  const int bA = g;
  const int bB = g + 32;

  __shared__ float tl[512 * 64];       // 128 KB: T[0..511][64m..64m+63]
  __shared__ float stgA[8][64];        // per-wave v-slice staging, batch A
  __shared__ float stgB[8][64];
  __shared__ float pA[8][64];          // partials
  __shared__ float pB[8][64];
  __shared__ int obsA[NT];
  __shared__ int obsB[NT];

  obsA[tid] = obs[bA * NT + tid];
  obsB[tid] = obs[bB * NT + tid];

  // stage my T-slice: rows k*8+oct, col jl (coalesced 256B per wave-instr)
#pragma unroll
  for (int k = 0; k < 64; ++k) {
    int row = k * 8 + oct;
    tl[row * 64 + jl] = trans[(size_t)row * NS + m * 64 + jl];
  }

  // t = 0 init: each wave stages its source slice of v0; member 0 checkpoints.
  {
    int o0A = obs[bA * NT];
    int o0B = obs[bB * NT];
    int s = ib * 64 + jl;
    float bs = start[s];
    stgA[oct][jl] = bs + emT[(size_t)o0A * NS + s];
    stgB[oct][jl] = bs + emT[(size_t)o0B * NS + s];
    if (m == 0) {
      float b0 = start[tid];
      v[(size_t)bA * NS + tid] = b0 + emT[(size_t)o0A * NS + tid];
      v[(size_t)bB * NS + tid] = b0 + emT[(size_t)o0B * NS + tid];
    }
  }
  __syncthreads();

  int* flA = flags + g * 16;      // words 0..7
  int* flB = flags + g * 16 + 8;  // words 8..15
  const float* tlp = tl + (size_t)(ib * 64) * 64 + jl;

  for (int t = 1; t < NT; ++t) {
    // emission prefetch (wave 0 consumes at EA/EB; in flight all step)
    float eA = 0.f, eB = 0.f;
    if (oct == 0) {
      eA = emT[(size_t)obsA[t] * NS + m * 64 + jl];
      eB = emT[(size_t)obsB[t] * NS + m * 64 + jl];
    }

    // ---- A gather (waves 1..7; wave0's stgA[0] set at EA(t-1)) ----
    if (t >= 2 && oct > 0) {
      int* f = flA + ib;
      while (__hip_atomic_load(f, __ATOMIC_RELAXED, __HIP_MEMORY_SCOPE_AGENT) < t - 1)
        __builtin_amdgcn_s_sleep(1);
      (void)__hip_atomic_load(f, __ATOMIC_ACQUIRE, __HIP_MEMORY_SCOPE_AGENT);
      float ga = __hip_atomic_load(v + ((size_t)(t - 1) * NB + bA) * NS + ib * 64 + jl,
                                   __ATOMIC_RELAXED, __HIP_MEMORY_SCOPE_AGENT);
      stgA[oct][jl] = ga;  // consumed by THIS wave only: no barrier needed
    }

    // ---- compute A: col j over i in [64*ib, 64*ib+64) ----
    {
      float a0 = -INFINITY, a1 = -INFINITY;
      const float4* sg = reinterpret_cast<const float4*>(stgA[oct]);
#pragma unroll
      for (int c = 0; c < 16; ++c) {
        float4 x = sg[c];  // wave-uniform broadcast
        a0 = fmaxf(a0, fmaxf(x.x + tlp[(4 * c + 0) * 64], x.y + tlp[(4 * c + 1) * 64]));
        a1 = fmaxf(a1, fmaxf(x.z + tlp[(4 * c + 2) * 64], x.w + tlp[(4 * c + 3) * 64]));
      }
      pA[oct][jl] = fmaxf(a0, a1);
    }
    __syncthreads();  // barrier1: pA complete

    // ---- EA (wave 0) || B poll+gather (waves 1..7) ----
    if (oct == 0) {
      float vn = fmaxf(fmaxf(fmaxf(pA[0][jl], pA[1][jl]), fmaxf(pA[2][jl], pA[3][jl])),
                       fmaxf(fmaxf(pA[4][jl], pA[5][jl]), fmaxf(pA[6][jl], pA[7][jl]))) + eA;
      stgA[0][jl] = vn;
      __hip_atomic_store(v + ((size_t)t * NB + bA) * NS + m * 64 + jl, vn,
                         __ATOMIC_RELAXED, __HIP_MEMORY_SCOPE_AGENT);
      if (jl == 0)  // release orders this wave's publish stores
        __hip_atomic_store(flA + m, t, __ATOMIC_RELEASE, __HIP_MEMORY_SCOPE_AGENT);
    } else if (t >= 2) {
      int* f = flB + ib;
      while (__hip_atomic_load(f, __ATOMIC_RELAXED, __HIP_MEMORY_SCOPE_AGENT) < t - 1)
        __builtin_amdgcn_s_sleep(1);
      (void)__hip_atomic_load(f, __ATOMIC_ACQUIRE, __HIP_MEMORY_SCOPE_AGENT);
      float gb = __hip_atomic_load(v + ((size_t)(t - 1) * NB + bB) * NS + ib * 64 + jl,
                                   __ATOMIC_RELAXED, __HIP_MEMORY_SCOPE_AGENT);
      stgB[oct][jl] = gb;
    }

    // ---- compute B (same T-slice) ----
    {
      float b0 = -INFINITY, b1 = -INFINITY;
      const float4* sg = reinterpret_cast<const float4*>(stgB[oct]);
#pragma unroll
      for (int c = 0; c < 16; ++c) {
        float4 x = sg[c];
        b0 = fmaxf(b0, fmaxf(x.x + tlp[(4 * c + 0) * 64], x.y + tlp[(4 * c + 1) * 64]));
        b1 = fmaxf(b1, fmaxf(x.z + tlp[(4 * c + 2) * 64], x.w + tlp[(4 * c + 3) * 64]));
      }
      pB[oct][jl] = fmaxf(b0, b1);
    }
    __syncthreads();  // barrier2: pB complete (EA also done)

    // ---- EB (wave 0) ----
    if (oct == 0) {
      float vn = fmaxf(fmaxf(fmaxf(pB[0][jl], pB[1][jl]), fmaxf(pB[2][jl], pB[3][jl])),
                       fmaxf(fmaxf(pB[4][jl], pB[5][jl]), fmaxf(pB[6][jl], pB[7][jl]))) + eB;
      stgB[0][jl] = vn;
      __hip_atomic_store(v + ((size_t)t * NB + bB) * NS + m * 64 + jl, vn,
                         __ATOMIC_RELAXED, __HIP_MEMORY_SCOPE_AGENT);
      if (jl == 0)
        __hip_atomic_store(flB + m, t, __ATOMIC_RELEASE, __HIP_MEMORY_SCOPE_AGENT);
    }
    __syncthreads();  // barrier3: pA/pB reuse guard for t+1
  }
}

// Backtrace: one wave per batch; recompute argmax with exact first-wins ties.
__global__ __launch_bounds__(64) void viterbi_bt(
    const float* __restrict__ v,      // [NT][NB][NS]
    const float* __restrict__ transT, // [NS][NS], transT[j][i] = trans[i][j]
    int* __restrict__ path)           // [NB][NT] int32
{
  const int b = blockIdx.x;
  const int lane = threadIdx.x;

  const float4* vrow = reinterpret_cast<const float4*>(v + ((size_t)(NT - 1) * NB + b) * NS);
  float val = -INFINITY;
  int idx = 0;
#pragma unroll
  for (int w = 0; w < 2; ++w) {
    float4 a = vrow[lane + 64 * w];
    int base = 4 * (lane + 64 * w);
    if (a.x > val) { val = a.x; idx = base + 0; }
    if (a.y > val) { val = a.y; idx = base + 1; }
    if (a.z > val) { val = a.z; idx = base + 2; }
    if (a.w > val) { val = a.w; idx = base + 3; }
  }
#pragma unroll
  for (int off = 32; off; off >>= 1) {
    float v2 = __shfl_down(val, off);
    int i2 = __shfl_down(idx, off);
    if (v2 > val || (v2 == val && i2 < idx)) { val = v2; idx = i2; }
  }
  int state = __shfl(idx, 0);
  if (lane == 0) path[b * NT + (NT - 1)] = state;

  float4 vp0, vp1;
  {
    const float4* vp = reinterpret_cast<const float4*>(v + ((size_t)(NT - 2) * NB + b) * NS);
    vp0 = vp[lane];
    vp1 = vp[lane + 64];
  }

  for (int t = NT - 1; t >= 1; --t) {
    float4 np0, np1;
    if (t >= 2) {
      const float4* vp = reinterpret_cast<const float4*>(v + ((size_t)(t - 2) * NB + b) * NS);
      np0 = vp[lane];
      np1 = vp[lane + 64];
    }
    const float4* tr = reinterpret_cast<const float4*>(transT + (size_t)state * NS);
    float4 t0 = tr[lane];
    float4 t1 = tr[lane + 64];

    float val2 = -INFINITY;
    int idx2 = 0;
    {
      float s0 = vp0.x + t0.x, s1 = vp0.y + t0.y, s2 = vp0.z + t0.z, s3 = vp0.w + t0.w;
      int base = 4 * lane;
      if (s0 > val2) { val2 = s0; idx2 = base + 0; }
      if (s1 > val2) { val2 = s1; idx2 = base + 1; }
      if (s2 > val2) { val2 = s2; idx2 = base + 2; }
      if (s3 > val2) { val2 = s3; idx2 = base + 3; }
    }
    {
      float s0 = vp1.x + t1.x, s1 = vp1.y + t1.y, s2 = vp1.z + t1.z, s3 = vp1.w + t1.w;
      int base = 4 * (lane + 64);
      if (s0 > val2) { val2 = s0; idx2 = base + 0; }
      if (s1 > val2) { val2 = s1; idx2 = base + 1; }
      if (s2 > val2) { val2 = s2; idx2 = base + 2; }
      if (s3 > val2) { val2 = s3; idx2 = base + 3; }
    }
#pragma unroll
    for (int off = 32; off; off >>= 1) {
      float v2 = __shfl_down(val2, off);
      int i2 = __shfl_down(idx2, off);
      if (v2 > val2 || (v2 == val2 && i2 < idx2)) { val2 = v2; idx2 = i2; }
    }
    state = __shfl(idx2, 0);
    if (lane == 0) path[b * NT + (t - 1)] = state;
    vp0 = np0;
    vp1 = np1;
  }
}

extern "C" void kernel_launch(void* const* d_in, const int* in_sizes, int n_in,
                              void* d_out, int out_size, void* d_ws, size_t ws_size,
                              hipStream_t stream) {
  const int* obs = (const int*)d_in[0];       // [64][512]
  const float* start = (const float*)d_in[1]; // [512]
  const float* trans = (const float*)d_in[2]; // [512][512]
  const float* emis = (const float*)d_in[3];  // [512][2048]
  int* path = (int*)d_out;                    // [64][512] int32

  char* ws = (char*)d_ws;
  float* emT = (float*)ws;                           // [2048][512] = 4 MB
  float* transT = (float*)(ws + (4ull << 20));       // [512][512]  = 1 MB
  float* v = (float*)(ws + (5ull << 20));            // [512][64][512] = 64 MB
  int* flags = (int*)(ws + (69ull << 20));           // [32][16] = 2 KB

  hipMemsetAsync(flags, 0, 32 * 16 * sizeof(int), stream);

  dim3 tb(32, 8);
  transpose_k<<<dim3(NE / 32, NS / 32), tb, 0, stream>>>(emis, emT, NS, NE);
  transpose_k<<<dim3(NS / 32, NS / 32), tb, 0, stream>>>(trans, transT, NS, NS);
  viterbi_fwd<<<256, 512, 0, stream>>>(obs, start, trans, emT, v, flags);
  viterbi_bt<<<NB, 64, 0, stream>>>(v, transT, path);
}

// Round 13
// 2817.383 us; speedup vs baseline: 5.6660x; 5.6660x over previous
//
#include <hip/hip_runtime.h>
#include <math.h>

#define NS 512
#define NE 2048
#define NB 64
#define NT 512

// out[c][r] = in[r][c]; rows, cols multiples of 32
__global__ __launch_bounds__(256) void transpose_k(const float* __restrict__ in,
                                                   float* __restrict__ out,
                                                   int rows, int cols) {
  __shared__ float tile[32][33];
  int c0 = blockIdx.x * 32;
  int r0 = blockIdx.y * 32;
  int tx = threadIdx.x;  // 0..31
  int ty = threadIdx.y;  // 0..7
#pragma unroll
  for (int k = 0; k < 32; k += 8) {
    tile[ty + k][tx] = in[(size_t)(r0 + ty + k) * cols + (c0 + tx)];
  }
  __syncthreads();
#pragma unroll
  for (int k = 0; k < 32; k += 8) {
    out[(size_t)(c0 + ty + k) * rows + (r0 + tx)] = tile[tx][ty + k];
  }
}

// Forward, 2-batch-fused column-slice. Grid 256 = 32 groups x 8 members
// (bid = g + 32*m -> all members of a group on one XCD). Member m owns output
// columns [64m,64m+64) for batches bA=g and bB=g+32. One pass per iteration
// streams the member's T-slice (512x64, 128KB) from L2 ONCE and accumulates
// partials for BOTH batches (each T value used twice from a short-lived reg —
// no bulk register/LDS residency, lessons R3/R4/R6/R11/R12).
// Thread (oct=tid>>6, jl=tid&63) covers column j=64m+jl; within each 64-row
// i-block p, it reduces i in [64p+8*oct, +8).
// Sync = R10's proven shape, paid once per TWO batch-steps:
//   local phase (p=m, no external dep) -> tid0-only poll of ONE counter
//   (R12 lesson: exactly one poller per block) -> barrier -> cooperative
//   gather (2 relaxed agent loads/thread, both batches) -> barrier ->
//   7 remote phases -> partials barrier -> E (wave0 reduce+publish both) ->
//   barrier -> tid0 fetch_add(release). Exchange medium = time-indexed
//   checkpoint v[t] (write-once); counter monotonic: cnt>=8k <=> all members
//   done iter k.
__global__ __launch_bounds__(512) void viterbi_fwd(
    const int* __restrict__ obs,     // [NB][NT]
    const float* __restrict__ start, // [NS]
    const float* __restrict__ trans, // [NS][NS]
    const float* __restrict__ emT,   // [NE][NS]
    float* __restrict__ v,           // [NT][NB][NS] checkpoints + exchange
    int* __restrict__ flags)         // [32][32], zeroed before launch
{
  const int g = blockIdx.x & 31;
  const int m = blockIdx.x >> 5;       // member 0..7
  const int tid = threadIdx.x;
  const int jl = tid & 63;
  const int oct = tid >> 6;            // wave 0..7
  const int j = m * 64 + jl;           // my output column (= state index)
  const int bA = g;
  const int bB = g + 32;

  __shared__ __align__(16) float vfA[NS];
  __shared__ __align__(16) float vfB[NS];
  __shared__ float pA[8][64];
  __shared__ float pB[8][64];
  __shared__ int obsA[NT];
  __shared__ int obsB[NT];

  obsA[tid] = obs[bA * NT + tid];
  obsB[tid] = obs[bB * NT + tid];

  // t = 0: full v0 for both batches in LDS; member 0 checkpoints.
  {
    int o0A = obs[bA * NT];
    int o0B = obs[bB * NT];
    float s0 = start[tid];
    float a = s0 + emT[(size_t)o0A * NS + tid];
    float b = s0 + emT[(size_t)o0B * NS + tid];
    vfA[tid] = a;
    vfB[tid] = b;
    if (m == 0) {
      v[(size_t)bA * NS + tid] = a;
      v[(size_t)bB * NS + tid] = b;
    }
  }
  __syncthreads();

  int* cnt = flags + g * 32;

  // fused 8-row phase over i-block p: 8 T loads, each used for A and B
#define PHASE(p)                                                               \
  {                                                                            \
    const int i0 = (p) * 64 + oct * 8;                                         \
    const float* tp = trans + (size_t)i0 * NS + j;                             \
    const float4* va = reinterpret_cast<const float4*>(vfA + i0);              \
    const float4* vb = reinterpret_cast<const float4*>(vfB + i0);              \
    _Pragma("unroll")                                                          \
    for (int c = 0; c < 2; ++c) {                                              \
      float t0 = tp[(size_t)(4 * c + 0) * NS];                                 \
      float t1 = tp[(size_t)(4 * c + 1) * NS];                                 \
      float t2 = tp[(size_t)(4 * c + 2) * NS];                                 \
      float t3 = tp[(size_t)(4 * c + 3) * NS];                                 \
      float4 xa = va[c];                                                       \
      float4 xb = vb[c];                                                       \
      accA = fmaxf(accA, fmaxf(fmaxf(xa.x + t0, xa.y + t1),                    \
                               fmaxf(xa.z + t2, xa.w + t3)));                  \
      accB = fmaxf(accB, fmaxf(fmaxf(xb.x + t0, xb.y + t1),                    \
                               fmaxf(xb.z + t2, xb.w + t3)));                  \
    }                                                                          \
  }

  for (int t = 1; t < NT; ++t) {
    // emission prefetch (wave 0, consumed at E — in flight the whole iter)
    float eA = 0.f, eB = 0.f;
    if (oct == 0) {
      eA = emT[(size_t)obsA[t] * NS + j];
      eB = emT[(size_t)obsB[t] * NS + j];
    }

    // ---- local phase: own i-block (p = m), no external dependency ----
    float accA = -INFINITY, accB = -INFINITY;
    PHASE(m)

    if (t >= 2) {
      // ---- single poller, single counter (R12 lesson) ----
      if (tid == 0) {
        const int tgt = 8 * (t - 1);
        while (__hip_atomic_load(cnt, __ATOMIC_RELAXED, __HIP_MEMORY_SCOPE_AGENT) < tgt)
          __builtin_amdgcn_s_sleep(1);
        (void)__hip_atomic_load(cnt, __ATOMIC_ACQUIRE, __HIP_MEMORY_SCOPE_AGENT);
      }
      __syncthreads();
      // ---- cooperative gather, both batches (2 relaxed loads/thread) ----
      if (tid < 448) {
        int r = tid >> 6;              // 0..6
        int p = (m + 1 + r) & 7;
        int o = tid & 63;
        float ga = __hip_atomic_load(v + ((size_t)(t - 1) * NB + bA) * NS + p * 64 + o,
                                     __ATOMIC_RELAXED, __HIP_MEMORY_SCOPE_AGENT);
        float gb = __hip_atomic_load(v + ((size_t)(t - 1) * NB + bB) * NS + p * 64 + o,
                                     __ATOMIC_RELAXED, __HIP_MEMORY_SCOPE_AGENT);
        vfA[p * 64 + o] = ga;
        vfB[p * 64 + o] = gb;
      }
      __syncthreads();
    }

    // ---- remote phases: stream the other 448 T rows, fused A+B ----
#pragma unroll
    for (int r = 1; r < 8; ++r) {
      PHASE((m + r) & 7)
    }
    pA[oct][jl] = accA;
    pB[oct][jl] = accB;
    __syncthreads();

    // ---- E: wave 0 reduces 8 partials, finalizes, publishes both ----
    if (oct == 0) {
      float vnA = fmaxf(fmaxf(fmaxf(pA[0][jl], pA[1][jl]), fmaxf(pA[2][jl], pA[3][jl])),
                        fmaxf(fmaxf(pA[4][jl], pA[5][jl]), fmaxf(pA[6][jl], pA[7][jl]))) + eA;
      float vnB = fmaxf(fmaxf(fmaxf(pB[0][jl], pB[1][jl]), fmaxf(pB[2][jl], pB[3][jl])),
                        fmaxf(fmaxf(pB[4][jl], pB[5][jl]), fmaxf(pB[6][jl], pB[7][jl]))) + eB;
      vfA[j] = vnA;
      vfB[j] = vnB;
      __hip_atomic_store(v + ((size_t)t * NB + bA) * NS + j, vnA,
                         __ATOMIC_RELAXED, __HIP_MEMORY_SCOPE_AGENT);
      __hip_atomic_store(v + ((size_t)t * NB + bB) * NS + j, vnB,
                         __ATOMIC_RELAXED, __HIP_MEMORY_SCOPE_AGENT);
    }
    __syncthreads();  // publish stores drained (vmcnt0/wave) + vf own-slice visible
    if (tid == 0)
      __hip_atomic_fetch_add(cnt, 1, __ATOMIC_RELEASE, __HIP_MEMORY_SCOPE_AGENT);
  }
#undef PHASE
}

// Backtrace: one wave per batch; recompute argmax with exact first-wins ties.
__global__ __launch_bounds__(64) void viterbi_bt(
    const float* __restrict__ v,      // [NT][NB][NS]
    const float* __restrict__ transT, // [NS][NS], transT[j][i] = trans[i][j]
    int* __restrict__ path)           // [NB][NT] int32
{
  const int b = blockIdx.x;
  const int lane = threadIdx.x;

  const float4* vrow = reinterpret_cast<const float4*>(v + ((size_t)(NT - 1) * NB + b) * NS);
  float val = -INFINITY;
  int idx = 0;
#pragma unroll
  for (int w = 0; w < 2; ++w) {
    float4 a = vrow[lane + 64 * w];
    int base = 4 * (lane + 64 * w);
    if (a.x > val) { val = a.x; idx = base + 0; }
    if (a.y > val) { val = a.y; idx = base + 1; }
    if (a.z > val) { val = a.z; idx = base + 2; }
    if (a.w > val) { val = a.w; idx = base + 3; }
  }
#pragma unroll
  for (int off = 32; off; off >>= 1) {
    float v2 = __shfl_down(val, off);
    int i2 = __shfl_down(idx, off);
    if (v2 > val || (v2 == val && i2 < idx)) { val = v2; idx = i2; }
  }
  int state = __shfl(idx, 0);
  if (lane == 0) path[b * NT + (NT - 1)] = state;

  float4 vp0, vp1;
  {
    const float4* vp = reinterpret_cast<const float4*>(v + ((size_t)(NT - 2) * NB + b) * NS);
    vp0 = vp[lane];
    vp1 = vp[lane + 64];
  }

  for (int t = NT - 1; t >= 1; --t) {
    float4 np0, np1;
    if (t >= 2) {
      const float4* vp = reinterpret_cast<const float4*>(v + ((size_t)(t - 2) * NB + b) * NS);
      np0 = vp[lane];
      np1 = vp[lane + 64];
    }
    const float4* tr = reinterpret_cast<const float4*>(transT + (size_t)state * NS);
    float4 t0 = tr[lane];
    float4 t1 = tr[lane + 64];

    float val2 = -INFINITY;
    int idx2 = 0;
    {
      float s0 = vp0.x + t0.x, s1 = vp0.y + t0.y, s2 = vp0.z + t0.z, s3 = vp0.w + t0.w;
      int base = 4 * lane;
      if (s0 > val2) { val2 = s0; idx2 = base + 0; }
      if (s1 > val2) { val2 = s1; idx2 = base + 1; }
      if (s2 > val2) { val2 = s2; idx2 = base + 2; }
      if (s3 > val2) { val2 = s3; idx2 = base + 3; }
    }
    {
      float s0 = vp1.x + t1.x, s1 = vp1.y + t1.y, s2 = vp1.z + t1.z, s3 = vp1.w + t1.w;
      int base = 4 * (lane + 64);
      if (s0 > val2) { val2 = s0; idx2 = base + 0; }
      if (s1 > val2) { val2 = s1; idx2 = base + 1; }
      if (s2 > val2) { val2 = s2; idx2 = base + 2; }
      if (s3 > val2) { val2 = s3; idx2 = base + 3; }
    }
#pragma unroll
    for (int off = 32; off; off >>= 1) {
      float v2 = __shfl_down(val2, off);
      int i2 = __shfl_down(idx2, off);
      if (v2 > val2 || (v2 == val2 && i2 < idx2)) { val2 = v2; idx2 = i2; }
    }
    state = __shfl(idx2, 0);
    if (lane == 0) path[b * NT + (t - 1)] = state;
    vp0 = np0;
    vp1 = np1;
  }
}

extern "C" void kernel_launch(void* const* d_in, const int* in_sizes, int n_in,
                              void* d_out, int out_size, void* d_ws, size_t ws_size,
                              hipStream_t stream) {
  const int* obs = (const int*)d_in[0];       // [64][512]
  const float* start = (const float*)d_in[1]; // [512]
  const float* trans = (const float*)d_in[2]; // [512][512]
  const float* emis = (const float*)d_in[3];  // [512][2048]
  int* path = (int*)d_out;                    // [64][512] int32

  char* ws = (char*)d_ws;
  float* emT = (float*)ws;                           // [2048][512] = 4 MB
  float* transT = (float*)(ws + (4ull << 20));       // [512][512]  = 1 MB
  float* v = (float*)(ws + (5ull << 20));            // [512][64][512] = 64 MB
  int* flags = (int*)(ws + (69ull << 20));           // [32][32] = 4 KB

  hipMemsetAsync(flags, 0, 32 * 32 * sizeof(int), stream);

  dim3 tb(32, 8);
  transpose_k<<<dim3(NE / 32, NS / 32), tb, 0, stream>>>(emis, emT, NS, NE);
  transpose_k<<<dim3(NS / 32, NS / 32), tb, 0, stream>>>(trans, transT, NS, NS);
  viterbi_fwd<<<256, 512, 0, stream>>>(obs, start, trans, emT, v, flags);
  viterbi_bt<<<NB, 64, 0, stream>>>(v, transT, path);
}

// Round 14
// 1131.956 us; speedup vs baseline: 14.1023x; 2.4890x over previous
//
#include <hip/hip_runtime.h>
#include <math.h>

#define NS 512
#define NE 2048
#define NB 64
#define NT 512
#define SENT 0x7FC0DEADu  // NaN payload; real v values are always finite

// out[c][r] = in[r][c]; rows, cols multiples of 32
__global__ __launch_bounds__(256) void transpose_k(const float* __restrict__ in,
                                                   float* __restrict__ out,
                                                   int rows, int cols) {
  __shared__ float tile[32][33];
  int c0 = blockIdx.x * 32;
  int r0 = blockIdx.y * 32;
  int tx = threadIdx.x;  // 0..31
  int ty = threadIdx.y;  // 0..7
#pragma unroll
  for (int k = 0; k < 32; k += 8) {
    tile[ty + k][tx] = in[(size_t)(r0 + ty + k) * cols + (c0 + tx)];
  }
  __syncthreads();
#pragma unroll
  for (int k = 0; k < 32; k += 8) {
    out[(size_t)(c0 + ty + k) * rows + (r0 + tx)] = tile[tx][ty + k];
  }
}

// Pre-fill v[1..NT) with the sentinel each call (slots are write-once per call;
// the harness does NOT re-poison between replays, so we must reset ourselves).
__global__ __launch_bounds__(256) void fill_sentinel(float* __restrict__ v) {
  uint4 s = make_uint4(SENT, SENT, SENT, SENT);
  uint4* p = reinterpret_cast<uint4*>(v + (size_t)NB * NS);
  const size_t n4 = (size_t)(NT - 1) * NB * NS / 4;
  for (size_t i = (size_t)blockIdx.x * blockDim.x + threadIdx.x; i < n4;
       i += (size_t)gridDim.x * blockDim.x)
    p[i] = s;
}

// Forward, 2-batch-fused column-slice with WAIT-FREE sentinel exchange.
// Grid 256 = 32 groups x 8 members (bid = g + 32*m). Member m owns output
// columns [64m,64m+64) for batches bA=g, bB=g+32; one pass streams its 128KB
// T-slice once per iteration, used for both batches.
// Exchange protocol (replaces R10-R13's flags/poll/release — those cost
// ~2.2us/iter in serialized IC round trips):
//   - v[t] slots are TIME-INDEXED and WRITE-ONCE; pre-filled with a NaN
//     sentinel; 4B stores are word-atomic; real values are never NaN.
//   - writers publish with relaxed agent-scope atomic stores;
//   - readers load and RETRY while any lane sees the sentinel (__any per
//     wave). Each word self-validates: no flags, no ordering, no RMW, no
//     poll round-trip. Steady-state sync+gather = ONE IC round trip.
__global__ __launch_bounds__(512) void viterbi_fwd(
    const int* __restrict__ obs,     // [NB][NT]
    const float* __restrict__ start, // [NS]
    const float* __restrict__ trans, // [NS][NS]
    const float* __restrict__ emT,   // [NE][NS]
    float* __restrict__ v)           // [NT][NB][NS] checkpoints + exchange
{
  const int g = blockIdx.x & 31;
  const int m = blockIdx.x >> 5;       // member 0..7
  const int tid = threadIdx.x;
  const int jl = tid & 63;
  const int oct = tid >> 6;            // wave 0..7
  const int j = m * 64 + jl;           // my output column (= state index)
  const int bA = g;
  const int bB = g + 32;

  __shared__ __align__(16) float vfA[NS];
  __shared__ __align__(16) float vfB[NS];
  __shared__ float pA[8][64];
  __shared__ float pB[8][64];
  __shared__ int obsA[NT];
  __shared__ int obsB[NT];

  obsA[tid] = obs[bA * NT + tid];
  obsB[tid] = obs[bB * NT + tid];

  // t = 0: full v0 for both batches in LDS; member 0 checkpoints (plain
  // stores fine: v[0] is read only by viterbi_bt after this kernel ends).
  {
    int o0A = obs[bA * NT];
    int o0B = obs[bB * NT];
    float s0 = start[tid];
    float a = s0 + emT[(size_t)o0A * NS + tid];
    float b = s0 + emT[(size_t)o0B * NS + tid];
    vfA[tid] = a;
    vfB[tid] = b;
    if (m == 0) {
      v[(size_t)bA * NS + tid] = a;
      v[(size_t)bB * NS + tid] = b;
    }
  }
  __syncthreads();

  // fused 8-row phase over i-block p: 8 T loads, each used for A and B
#define PHASE(p)                                                               \
  {                                                                            \
    const int i0 = (p) * 64 + oct * 8;                                         \
    const float* tp = trans + (size_t)i0 * NS + j;                             \
    const float4* va = reinterpret_cast<const float4*>(vfA + i0);              \
    const float4* vb = reinterpret_cast<const float4*>(vfB + i0);              \
    _Pragma("unroll")                                                          \
    for (int c = 0; c < 2; ++c) {                                              \
      float t0 = tp[(size_t)(4 * c + 0) * NS];                                 \
      float t1 = tp[(size_t)(4 * c + 1) * NS];                                 \
      float t2 = tp[(size_t)(4 * c + 2) * NS];                                 \
      float t3 = tp[(size_t)(4 * c + 3) * NS];                                 \
      float4 xa = va[c];                                                       \
      float4 xb = vb[c];                                                       \
      accA = fmaxf(accA, fmaxf(fmaxf(xa.x + t0, xa.y + t1),                    \
                               fmaxf(xa.z + t2, xa.w + t3)));                  \
      accB = fmaxf(accB, fmaxf(fmaxf(xb.x + t0, xb.y + t1),                    \
                               fmaxf(xb.z + t2, xb.w + t3)));                  \
    }                                                                          \
  }

  for (int t = 1; t < NT; ++t) {
    // emission prefetch: wave0 consumes eA, wave1 consumes eB at E
    float eA = 0.f, eB = 0.f;
    if (oct == 0) eA = emT[(size_t)obsA[t] * NS + j];
    if (oct == 1) eB = emT[(size_t)obsB[t] * NS + j];

    // ---- local phase: own i-block, no external dependency ----
    float accA = -INFINITY, accB = -INFINITY;
    PHASE(m)

    if (t >= 2) {
      // ---- sentinel-validated cooperative gather (waves 0..6) ----
      if (tid < 448) {
        int r = tid >> 6;              // 0..6
        int p = (m + 1 + r) & 7;
        int o = tid & 63;
        const float* aA = v + ((size_t)(t - 1) * NB + bA) * NS + p * 64 + o;
        const float* aB = v + ((size_t)(t - 1) * NB + bB) * NS + p * 64 + o;
        float ga, gb;
        for (;;) {
          ga = __hip_atomic_load(aA, __ATOMIC_RELAXED, __HIP_MEMORY_SCOPE_AGENT);
          gb = __hip_atomic_load(aB, __ATOMIC_RELAXED, __HIP_MEMORY_SCOPE_AGENT);
          if (__any(__float_as_uint(ga) == SENT || __float_as_uint(gb) == SENT)) {
            __builtin_amdgcn_s_sleep(1);
            continue;
          }
          break;
        }
        vfA[p * 64 + o] = ga;
        vfB[p * 64 + o] = gb;
      }
      __syncthreads();
    }

    // ---- remote phases: stream the other 448 T rows, fused A+B ----
#pragma unroll
    for (int r = 1; r < 8; ++r) {
      PHASE((m + r) & 7)
    }
    pA[oct][jl] = accA;
    pB[oct][jl] = accB;
    __syncthreads();

    // ---- E: wave0 finalizes/publishes A; wave1 finalizes/publishes B ----
    if (oct == 0) {
      float vnA = fmaxf(fmaxf(fmaxf(pA[0][jl], pA[1][jl]), fmaxf(pA[2][jl], pA[3][jl])),
                        fmaxf(fmaxf(pA[4][jl], pA[5][jl]), fmaxf(pA[6][jl], pA[7][jl]))) + eA;
      vfA[j] = vnA;
      __hip_atomic_store(v + ((size_t)t * NB + bA) * NS + j, vnA,
                         __ATOMIC_RELAXED, __HIP_MEMORY_SCOPE_AGENT);
    } else if (oct == 1) {
      float vnB = fmaxf(fmaxf(fmaxf(pB[0][jl], pB[1][jl]), fmaxf(pB[2][jl], pB[3][jl])),
                        fmaxf(fmaxf(pB[4][jl], pB[5][jl]), fmaxf(pB[6][jl], pB[7][jl]))) + eB;
      vfB[j] = vnB;
      __hip_atomic_store(v + ((size_t)t * NB + bB) * NS + j, vnB,
                         __ATOMIC_RELAXED, __HIP_MEMORY_SCOPE_AGENT);
    }
    __syncthreads();  // vf own-slices visible for next local phase; pA/pB reusable
  }
#undef PHASE
}

// Backtrace: one wave per batch; recompute argmax with exact first-wins ties.
__global__ __launch_bounds__(64) void viterbi_bt(
    const float* __restrict__ v,      // [NT][NB][NS]
    const float* __restrict__ transT, // [NS][NS], transT[j][i] = trans[i][j]
    int* __restrict__ path)           // [NB][NT] int32
{
  const int b = blockIdx.x;
  const int lane = threadIdx.x;

  const float4* vrow = reinterpret_cast<const float4*>(v + ((size_t)(NT - 1) * NB + b) * NS);
  float val = -INFINITY;
  int idx = 0;
#pragma unroll
  for (int w = 0; w < 2; ++w) {
    float4 a = vrow[lane + 64 * w];
    int base = 4 * (lane + 64 * w);
    if (a.x > val) { val = a.x; idx = base + 0; }
    if (a.y > val) { val = a.y; idx = base + 1; }
    if (a.z > val) { val = a.z; idx = base + 2; }
    if (a.w > val) { val = a.w; idx = base + 3; }
  }
#pragma unroll
  for (int off = 32; off; off >>= 1) {
    float v2 = __shfl_down(val, off);
    int i2 = __shfl_down(idx, off);
    if (v2 > val || (v2 == val && i2 < idx)) { val = v2; idx = i2; }
  }
  int state = __shfl(idx, 0);
  if (lane == 0) path[b * NT + (NT - 1)] = state;

  float4 vp0, vp1;
  {
    const float4* vp = reinterpret_cast<const float4*>(v + ((size_t)(NT - 2) * NB + b) * NS);
    vp0 = vp[lane];
    vp1 = vp[lane + 64];
  }

  for (int t = NT - 1; t >= 1; --t) {
    float4 np0, np1;
    if (t >= 2) {
      const float4* vp = reinterpret_cast<const float4*>(v + ((size_t)(t - 2) * NB + b) * NS);
      np0 = vp[lane];
      np1 = vp[lane + 64];
    }
    const float4* tr = reinterpret_cast<const float4*>(transT + (size_t)state * NS);
    float4 t0 = tr[lane];
    float4 t1 = tr[lane + 64];

    float val2 = -INFINITY;
    int idx2 = 0;
    {
      float s0 = vp0.x + t0.x, s1 = vp0.y + t0.y, s2 = vp0.z + t0.z, s3 = vp0.w + t0.w;
      int base = 4 * lane;
      if (s0 > val2) { val2 = s0; idx2 = base + 0; }
      if (s1 > val2) { val2 = s1; idx2 = base + 1; }
      if (s2 > val2) { val2 = s2; idx2 = base + 2; }
      if (s3 > val2) { val2 = s3; idx2 = base + 3; }
    }
    {
      float s0 = vp1.x + t1.x, s1 = vp1.y + t1.y, s2 = vp1.z + t1.z, s3 = vp1.w + t1.w;
      int base = 4 * (lane + 64);
      if (s0 > val2) { val2 = s0; idx2 = base + 0; }
      if (s1 > val2) { val2 = s1; idx2 = base + 1; }
      if (s2 > val2) { val2 = s2; idx2 = base + 2; }
      if (s3 > val2) { val2 = s3; idx2 = base + 3; }
    }
#pragma unroll
    for (int off = 32; off; off >>= 1) {
      float v2 = __shfl_down(val2, off);
      int i2 = __shfl_down(idx2, off);
      if (v2 > val2 || (v2 == val2 && i2 < idx2)) { val2 = v2; idx2 = i2; }
    }
    state = __shfl(idx2, 0);
    if (lane == 0) path[b * NT + (t - 1)] = state;
    vp0 = np0;
    vp1 = np1;
  }
}

extern "C" void kernel_launch(void* const* d_in, const int* in_sizes, int n_in,
                              void* d_out, int out_size, void* d_ws, size_t ws_size,
                              hipStream_t stream) {
  const int* obs = (const int*)d_in[0];       // [64][512]
  const float* start = (const float*)d_in[1]; // [512]
  const float* trans = (const float*)d_in[2]; // [512][512]
  const float* emis = (const float*)d_in[3];  // [512][2048]
  int* path = (int*)d_out;                    // [64][512] int32

  char* ws = (char*)d_ws;
  float* emT = (float*)ws;                           // [2048][512] = 4 MB
  float* transT = (float*)(ws + (4ull << 20));       // [512][512]  = 1 MB
  float* v = (float*)(ws + (5ull << 20));            // [512][64][512] = 64 MB

  fill_sentinel<<<1024, 256, 0, stream>>>(v);

  dim3 tb(32, 8);
  transpose_k<<<dim3(NE / 32, NS / 32), tb, 0, stream>>>(emis, emT, NS, NE);
  transpose_k<<<dim3(NS / 32, NS / 32), tb, 0, stream>>>(trans, transT, NS, NS);
  viterbi_fwd<<<256, 512, 0, stream>>>(obs, start, trans, emT, v);
  viterbi_bt<<<NB, 64, 0, stream>>>(v, transT, path);
}

// Round 15
// 1035.738 us; speedup vs baseline: 15.4124x; 1.0929x over previous
//
#include <hip/hip_runtime.h>
#include <math.h>

#define NS 512
#define NE 2048
#define NB 64
#define NT 512
#define SENT 0x7FC0DEADu  // NaN payload; real v values are always finite

// out[c][r] = in[r][c]; rows, cols multiples of 32
__global__ __launch_bounds__(256) void transpose_k(const float* __restrict__ in,
                                                   float* __restrict__ out,
                                                   int rows, int cols) {
  __shared__ float tile[32][33];
  int c0 = blockIdx.x * 32;
  int r0 = blockIdx.y * 32;
  int tx = threadIdx.x;  // 0..31
  int ty = threadIdx.y;  // 0..7
#pragma unroll
  for (int k = 0; k < 32; k += 8) {
    tile[ty + k][tx] = in[(size_t)(r0 + ty + k) * cols + (c0 + tx)];
  }
  __syncthreads();
#pragma unroll
  for (int k = 0; k < 32; k += 8) {
    out[(size_t)(c0 + ty + k) * rows + (r0 + tx)] = tile[tx][ty + k];
  }
}

// Pre-fill v[1..NT) with the sentinel each call (slots are write-once per call;
// harness does not re-poison between replays).
__global__ __launch_bounds__(256) void fill_sentinel(float* __restrict__ v) {
  uint4 s = make_uint4(SENT, SENT, SENT, SENT);
  uint4* p = reinterpret_cast<uint4*>(v + (size_t)NB * NS);
  const size_t n4 = (size_t)(NT - 1) * NB * NS / 4;
  for (size_t i = (size_t)blockIdx.x * blockDim.x + threadIdx.x; i < n4;
       i += (size_t)gridDim.x * blockDim.x)
    p[i] = s;
}

// Forward, 1-batch/group column-slice, sentinel exchange (R14 protocol),
// 2 blocks/CU. Grid 512 = 64 groups x 8 members (bid = g + 64*m -> members
// same XCD). Member m owns columns [64m,64m+64) of batch g. R13 showed
// wall = 511 * per-group iter latency -> shrink the iter: compute/iter halves
// vs R14's fused pair; one block's sync latency hides under the co-resident
// block's compute (16 waves/CU).
// Exchange: v[t] time-indexed write-once slots, NaN-sentinel prefilled,
// relaxed agent stores to publish, retry-while-sentinel loads to consume.
__global__ __launch_bounds__(512) void viterbi_fwd(
    const int* __restrict__ obs,     // [NB][NT]
    const float* __restrict__ start, // [NS]
    const float* __restrict__ trans, // [NS][NS]
    const float* __restrict__ emT,   // [NE][NS]
    float* __restrict__ v)           // [NT][NB][NS] checkpoints + exchange
{
  const int g = blockIdx.x & 63;
  const int m = blockIdx.x >> 6;       // member 0..7
  const int tid = threadIdx.x;
  const int jl = tid & 63;
  const int oct = tid >> 6;            // wave 0..7
  const int j = m * 64 + jl;           // my output column (= state index)

  __shared__ __align__(16) float vf[NS];
  __shared__ float part[8][64];
  __shared__ int obs_s[NT];

  obs_s[tid] = obs[g * NT + tid];

  // t = 0: full v0 in LDS; member 0 checkpoints (plain store: read only by bt).
  {
    int o0 = obs[g * NT];
    float a = start[tid] + emT[(size_t)o0 * NS + tid];
    vf[tid] = a;
    if (m == 0) v[(size_t)g * NS + tid] = a;
  }
  __syncthreads();

  // 8-row phase over i-block p: wave oct covers rows [64p+8*oct, +8)
#define PHASE(p)                                                               \
  {                                                                            \
    const int i0 = (p) * 64 + oct * 8;                                         \
    const float* tp = trans + (size_t)i0 * NS + j;                             \
    const float4* va = reinterpret_cast<const float4*>(vf + i0);               \
    _Pragma("unroll")                                                          \
    for (int c = 0; c < 2; ++c) {                                              \
      float t0 = tp[(size_t)(4 * c + 0) * NS];                                 \
      float t1 = tp[(size_t)(4 * c + 1) * NS];                                 \
      float t2 = tp[(size_t)(4 * c + 2) * NS];                                 \
      float t3 = tp[(size_t)(4 * c + 3) * NS];                                 \
      float4 xa = va[c];                                                       \
      acc = fmaxf(acc, fmaxf(fmaxf(xa.x + t0, xa.y + t1),                      \
                             fmaxf(xa.z + t2, xa.w + t3)));                    \
    }                                                                          \
  }

  for (int t = 1; t < NT; ++t) {
    float e = 0.f;
    if (oct == 0) e = emT[(size_t)obs_s[t] * NS + j];

    // ---- local phase: own i-block, no external dependency ----
    float acc = -INFINITY;
    PHASE(m)

    if (t >= 2) {
      // ---- sentinel-validated cooperative gather (1 load/thread) ----
      if (tid < 448) {
        int r = tid >> 6;              // 0..6
        int p = (m + 1 + r) & 7;
        int o = tid & 63;
        const float* ap = v + ((size_t)(t - 1) * NB + g) * NS + p * 64 + o;
        float ga;
        for (;;) {
          ga = __hip_atomic_load(ap, __ATOMIC_RELAXED, __HIP_MEMORY_SCOPE_AGENT);
          if (__any(__float_as_uint(ga) == SENT)) {
            __builtin_amdgcn_s_sleep(1);
            continue;
          }
          break;
        }
        vf[p * 64 + o] = ga;
      }
      __syncthreads();
    }

    // ---- remote phases ----
#pragma unroll
    for (int r = 1; r < 8; ++r) {
      PHASE((m + r) & 7)
    }
    part[oct][jl] = acc;
    __syncthreads();

    // ---- E: wave0 reduces, finalizes, publishes ----
    if (oct == 0) {
      float vn = fmaxf(fmaxf(fmaxf(part[0][jl], part[1][jl]), fmaxf(part[2][jl], part[3][jl])),
                       fmaxf(fmaxf(part[4][jl], part[5][jl]), fmaxf(part[6][jl], part[7][jl]))) + e;
      vf[j] = vn;
      __hip_atomic_store(v + ((size_t)t * NB + g) * NS + j, vn,
                         __ATOMIC_RELAXED, __HIP_MEMORY_SCOPE_AGENT);
    }
    __syncthreads();  // vf own-slice visible for next local phase; part reusable
  }
#undef PHASE
}

// Backtrace: one wave per batch. Lane l covers CONTIGUOUS states [8l, 8l+8).
// Argmax chain per step: local value-max tree (VALU) -> 6-level shfl_xor
// butterfly on VALUE only -> ballot(first lane with match, scalar ffs) ->
// ONE shfl broadcast. Exact first-wins: ascending contiguous coverage +
// descending local select + lowest-lane ballot pick.
__global__ __launch_bounds__(64) void viterbi_bt(
    const float* __restrict__ v,      // [NT][NB][NS]
    const float* __restrict__ transT, // [NS][NS], transT[j][i] = trans[i][j]
    int* __restrict__ path)           // [NB][NT] int32
{
  const int b = blockIdx.x;
  const int lane = threadIdx.x;

  // ---- argmax over final v row ----
  int state;
  {
    const float4* vr = reinterpret_cast<const float4*>(v + ((size_t)(NT - 1) * NB + b) * NS);
    float4 a = vr[2 * lane];
    float4 c = vr[2 * lane + 1];
    float s0 = a.x, s1 = a.y, s2 = a.z, s3 = a.w;
    float s4 = c.x, s5 = c.y, s6 = c.z, s7 = c.w;
    float lm = fmaxf(fmaxf(fmaxf(s0, s1), fmaxf(s2, s3)),
                     fmaxf(fmaxf(s4, s5), fmaxf(s6, s7)));
    float M = lm;
#pragma unroll
    for (int off = 1; off < 64; off <<= 1) M = fmaxf(M, __shfl_xor(M, off));
    int k = 0;
    if (s7 == M) k = 7;
    if (s6 == M) k = 6;
    if (s5 == M) k = 5;
    if (s4 == M) k = 4;
    if (s3 == M) k = 3;
    if (s2 == M) k = 2;
    if (s1 == M) k = 1;
    if (s0 == M) k = 0;
    unsigned long long bal = __ballot(lm == M);
    int first_lane = __ffsll(bal) - 1;
    state = __shfl(8 * lane + k, first_lane);
  }
  if (lane == 0) path[b * NT + (NT - 1)] = state;

  // prefetch v[T-2] row
  float4 vp0, vp1;
  {
    const float4* vp = reinterpret_cast<const float4*>(v + ((size_t)(NT - 2) * NB + b) * NS);
    vp0 = vp[2 * lane];
    vp1 = vp[2 * lane + 1];
  }

  for (int t = NT - 1; t >= 1; --t) {
    float4 np0, np1;
    if (t >= 2) {
      const float4* vp = reinterpret_cast<const float4*>(v + ((size_t)(t - 2) * NB + b) * NS);
      np0 = vp[2 * lane];
      np1 = vp[2 * lane + 1];
    }
    const float4* tr = reinterpret_cast<const float4*>(transT + (size_t)state * NS);
    float4 t0 = tr[2 * lane];
    float4 t1 = tr[2 * lane + 1];

    float s0 = vp0.x + t0.x, s1 = vp0.y + t0.y, s2 = vp0.z + t0.z, s3 = vp0.w + t0.w;
    float s4 = vp1.x + t1.x, s5 = vp1.y + t1.y, s6 = vp1.z + t1.z, s7 = vp1.w + t1.w;
    float lm = fmaxf(fmaxf(fmaxf(s0, s1), fmaxf(s2, s3)),
                     fmaxf(fmaxf(s4, s5), fmaxf(s6, s7)));
    float M = lm;
#pragma unroll
    for (int off = 1; off < 64; off <<= 1) M = fmaxf(M, __shfl_xor(M, off));
    int k = 0;
    if (s7 == M) k = 7;
    if (s6 == M) k = 6;
    if (s5 == M) k = 5;
    if (s4 == M) k = 4;
    if (s3 == M) k = 3;
    if (s2 == M) k = 2;
    if (s1 == M) k = 1;
    if (s0 == M) k = 0;
    unsigned long long bal = __ballot(lm == M);
    int first_lane = __ffsll(bal) - 1;
    state = __shfl(8 * lane + k, first_lane);

    if (lane == 0) path[b * NT + (t - 1)] = state;
    vp0 = np0;
    vp1 = np1;
  }
}

extern "C" void kernel_launch(void* const* d_in, const int* in_sizes, int n_in,
                              void* d_out, int out_size, void* d_ws, size_t ws_size,
                              hipStream_t stream) {
  const int* obs = (const int*)d_in[0];       // [64][512]
  const float* start = (const float*)d_in[1]; // [512]
  const float* trans = (const float*)d_in[2]; // [512][512]
  const float* emis = (const float*)d_in[3];  // [512][2048]
  int* path = (int*)d_out;                    // [64][512] int32

  char* ws = (char*)d_ws;
  float* emT = (float*)ws;                           // [2048][512] = 4 MB
  float* transT = (float*)(ws + (4ull << 20));       // [512][512]  = 1 MB
  float* v = (float*)(ws + (5ull << 20));            // [512][64][512] = 64 MB

  fill_sentinel<<<1024, 256, 0, stream>>>(v);

  dim3 tb(32, 8);
  transpose_k<<<dim3(NE / 32, NS / 32), tb, 0, stream>>>(emis, emT, NS, NE);
  transpose_k<<<dim3(NS / 32, NS / 32), tb, 0, stream>>>(trans, transT, NS, NS);
  viterbi_fwd<<<512, 512, 0, stream>>>(obs, start, trans, emT, v);
  viterbi_bt<<<NB, 64, 0, stream>>>(v, transT, path);
}